// Round 9
// baseline (192.109 us; speedup 1.0000x reference)
//
#include <hip/hip_runtime.h>
#include <cstdint>
#include <cstddef>

#define B 4096
#define D 128
#define MARGIN_F 0.2f
#define CW 256            // per-row candidate capacity

typedef short bf16x8 __attribute__((ext_vector_type(8)));
typedef float f32x4 __attribute__((ext_vector_type(4)));
typedef uint32_t u32x4 __attribute__((ext_vector_type(4)));

// order-preserving float->uint (ascending uint == ascending float)
__device__ __forceinline__ uint32_t xform_key(float f) {
    uint32_t u = __float_as_uint(f);
    return u ^ (uint32_t)((((int32_t)u) >> 31) | 0x80000000);
}
// decode 16-bit truncated key (bucket center under round-to-nearest encode)
__device__ __forceinline__ float unxform16(uint32_t k16) {
    uint32_t u = k16 << 16;
    u = (u & 0x80000000u) ? (u ^ 0x80000000u) : ~u;
    return __uint_as_float(u);
}
__device__ __forceinline__ unsigned short f2bf(float f) {   // round-nearest-even
    uint32_t u = __float_as_uint(f);
    return (unsigned short)((u + 0x7FFFu + ((u >> 16) & 1u)) >> 16);
}

// fused: zero out, sq[i] = ||R[i]||^2, R -> Rb (bf16 rne)
__global__ __launch_bounds__(256) void prep_kernel(const float* __restrict__ R,
                                                   float* __restrict__ sq,
                                                   unsigned short* __restrict__ Rb,
                                                   float* __restrict__ out) {
    if (blockIdx.x == 0 && threadIdx.x == 0) out[0] = 0.0f;
    int wave = threadIdx.x >> 6;
    int lane = threadIdx.x & 63;
    int row  = blockIdx.x * 4 + wave;
    const float2* R2 = (const float2*)R + (size_t)row * (D / 2);
    float2 v = R2[lane];
    ushort2 o; o.x = f2bf(v.x); o.y = f2bf(v.y);
    *(ushort2*)(Rb + (size_t)row * D + lane * 2) = o;
    float s = v.x * v.x + v.y * v.y;
#pragma unroll
    for (int off = 32; off > 0; off >>= 1) s += __shfl_down(s, off);
    if (lane == 0) sq[row] = s;
}

// r7's LDS-staged bf16 MFMA gram + dist/margin -> 16-bit keys,
// with NON-TEMPORAL key stores (push lines out of producer L2 -> no
// cross-XCD dirty-line round-trips for the consumer).
__global__ __launch_bounds__(256) void gemm_sim_mfma(const unsigned short* __restrict__ Rb,
                                                     const float* __restrict__ sq,
                                                     const int* __restrict__ labels,
                                                     unsigned short* __restrict__ simk) {
    __shared__ unsigned short sAB[32768];   // 64KB: A tile [0,16384), B tile [16384,32768)

    const int tid  = threadIdx.x;
    const int wid  = tid >> 6, lane = tid & 63;
    const int q    = lane >> 4, t = lane & 15;
    const int Ay0  = blockIdx.y * 128;
    const int Bx0  = blockIdx.x * 128;
    const int m0   = (wid >> 1) * 64;
    const int n0   = (wid & 1) * 64;

    // stage: slot s=(r<<4)|p holds global chunk (p ^ (r&15)) of row r
#pragma unroll
    for (int it = 0; it < 16; ++it) {
        int s = (wid * 16 + it) * 64 + lane;        // 0..4095
        int local = s & 2047;
        int r = local >> 4;
        int p = local & 15;
        int srcrow = ((s < 2048) ? Ay0 : Bx0) + r;
        const uint4* src = (const uint4*)(Rb + (size_t)srcrow * D + ((p ^ (r & 15)) << 3));
        *(uint4*)(&sAB[(size_t)s * 8]) = *src;
    }
    __syncthreads();

    f32x4 acc[4][4];
#pragma unroll
    for (int mi = 0; mi < 4; ++mi)
#pragma unroll
        for (int ni = 0; ni < 4; ++ni) acc[mi][ni] = (f32x4)0.0f;

#pragma unroll
    for (int kq = 0; kq < 4; ++kq) {
        bf16x8 af[4], bfr[4];
        const int ksw = (kq * 4 + q);
#pragma unroll
        for (int mi = 0; mi < 4; ++mi) {
            int r = m0 + mi * 16 + t;
            af[mi] = *(bf16x8*)(&sAB[(size_t)r * 128 + ((ksw ^ t) << 3)]);
        }
#pragma unroll
        for (int ni = 0; ni < 4; ++ni) {
            int r = n0 + ni * 16 + t;
            bfr[ni] = *(bf16x8*)(&sAB[16384 + (size_t)r * 128 + ((ksw ^ t) << 3)]);
        }
#pragma unroll
        for (int mi = 0; mi < 4; ++mi)
#pragma unroll
            for (int ni = 0; ni < 4; ++ni)
                acc[mi][ni] = __builtin_amdgcn_mfma_f32_16x16x32_bf16(
                    af[mi], bfr[ni], acc[mi][ni], 0, 0, 0);
    }

    __syncthreads();   // staging LDS dead; reuse per-wave for epilogue transpose

    const int epi0 = wid * 4608;            // 64*72 ushorts per wave
    float sqc[4]; int lc[4];
#pragma unroll
    for (int ni = 0; ni < 4; ++ni) {
        sqc[ni] = sq[Bx0 + n0 + ni * 16 + t];
        lc[ni]  = labels[Bx0 + n0 + ni * 16 + t];
    }
#pragma unroll
    for (int mi = 0; mi < 4; ++mi) {
#pragma unroll
        for (int r = 0; r < 4; ++r) {
            int lrow = mi * 16 + q * 4 + r;
            int grow = Ay0 + m0 + lrow;
            float sqr = sq[grow];
            int   lr  = labels[grow];
#pragma unroll
            for (int ni = 0; ni < 4; ++ni) {
                float g  = acc[mi][ni][r];
                float d2 = fmaxf(sqr + sqc[ni] - 2.0f * g, 0.0f);
                float dist = (d2 > 0.0f) ? sqrtf(d2) : 0.0f;
                float s = -dist + ((lr == lc[ni]) ? 0.0f : MARGIN_F);
                uint32_t key = xform_key(s);           // sim <= 0.2 -> no ovf on +0x8000
                sAB[epi0 + lrow * 72 + ni * 16 + t] =
                    (unsigned short)((key + 0x8000u) >> 16);
            }
        }
    }
#pragma unroll
    for (int it = 0; it < 8; ++it) {
        int rr = it * 8 + (lane >> 3);
        int cc = (lane & 7) * 8;
        u32x4 v = *(u32x4*)(&sAB[epi0 + rr * 72 + cc]);
        __builtin_nontemporal_store(
            v, (u32x4*)(simk + (size_t)(Ay0 + m0 + rr) * B + Bx0 + n0 + cc));
    }
}

// ONE WAVE PER BLOCK, one row per block. All 8 kv loads issued up front
// (nontemporal), labels after -> max MLP. comb = (u16<<12)|(4095-j).
__global__ __launch_bounds__(64, 8) void row_loss_w64(const unsigned short* __restrict__ simk,
                                                      const int* __restrict__ labels,
                                                      float* __restrict__ out) {
    __shared__ uint32_t cand_c[CW];   // comb | (match<<31)
    __shared__ int cnt;

    const int lane = threadIdx.x;
    const int row  = blockIdx.x;
    if (lane == 0) cnt = 0;

    const u32x4* pv = (const u32x4*)(simk + (size_t)row * B);
    const int4*  lv = (const int4*)labels;
    const int li = labels[row];

    // phase A1: all 8 row loads in flight before anything else
    u32x4 kv[8];
#pragma unroll
    for (int q = 0; q < 8; ++q)
        kv[q] = __builtin_nontemporal_load(pv + q * 64 + lane);

    // phase A2: labels -> match bits; top-2 from arrived kv
    uint64_t mbits = 0;
    uint32_t t1 = 0, t2 = 0;
#pragma unroll
    for (int q = 0; q < 8; ++q) {
        const int lb = (q * 64 + lane) * 2;
        int4 la = lv[lb], lc = lv[lb + 1];
        uint32_t u[8] = {kv[q].x & 0xFFFFu, kv[q].x >> 16,
                         kv[q].y & 0xFFFFu, kv[q].y >> 16,
                         kv[q].z & 0xFFFFu, kv[q].z >> 16,
                         kv[q].w & 0xFFFFu, kv[q].w >> 16};
#pragma unroll
        for (int c = 0; c < 8; ++c) {
            uint32_t mn = min(t1, u[c]);
            t1 = max(t1, u[c]);
            t2 = max(t2, mn);
        }
        mbits |= (uint64_t)(la.x == li) << (q * 8 + 0);
        mbits |= (uint64_t)(la.y == li) << (q * 8 + 1);
        mbits |= (uint64_t)(la.z == li) << (q * 8 + 2);
        mbits |= (uint64_t)(la.w == li) << (q * 8 + 3);
        mbits |= (uint64_t)(lc.x == li) << (q * 8 + 4);
        mbits |= (uint64_t)(lc.y == li) << (q * 8 + 5);
        mbits |= (uint64_t)(lc.z == li) << (q * 8 + 6);
        mbits |= (uint64_t)(lc.w == li) << (q * 8 + 7);
    }

    int kloc = __popcll(mbits);
#pragma unroll
    for (int off = 32; off > 0; off >>= 1) kloc += __shfl_xor(kloc, off);
    const int k = kloc;
    const float kf = (float)k;

    // ballot binary search: T = k-th largest of the 128-subset (<= true k-th)
    const int kneed = min(k, 128);
    uint32_t T = 0;
#pragma unroll
    for (int b = 15; b >= 0; --b) {
        uint32_t g = T | (1u << b);
        int c = __popcll(__ballot(t1 >= g)) + __popcll(__ballot(t2 >= g));
        if (c >= kneed) T = g;
    }
    const uint32_t combT = T << 12;

    // gather candidates = {u >= T} U {matches}; comb = (u<<12)|(4095-j)
#pragma unroll
    for (int q = 0; q < 8; ++q) {
        uint32_t u[8] = {kv[q].x & 0xFFFFu, kv[q].x >> 16,
                         kv[q].y & 0xFFFFu, kv[q].y >> 16,
                         kv[q].z & 0xFFFFu, kv[q].z >> 16,
                         kv[q].w & 0xFFFFu, kv[q].w >> 16};
        int jb = (q * 64 + lane) * 8;
#pragma unroll
        for (int c = 0; c < 8; ++c) {
            int e = q * 8 + c;
            uint32_t m = (uint32_t)((mbits >> e) & 1);
            if (u[c] >= T || m) {
                int p = atomicAdd(&cnt, 1);
                if (p < CW)
                    cand_c[p] = (u[c] << 12) | (uint32_t)(4095 - (jb + c)) | (m << 31);
            }
        }
    }
    const int ncand = min(cnt, CW);

    float facc = 0.0f;

    // candidate-internal exact ranks for u >= T (every beater is a candidate)
    for (int s = lane; s < ncand; s += 64) {
        uint32_t cs = cand_c[s];
        uint32_t comb = cs & 0x7FFFFFFFu;
        int m = (int)(cs >> 31);
        if (comb >= combT) {
            int c2 = 0;
            for (int c = 0; c < ncand; ++c)
                c2 += ((cand_c[c] & 0x7FFFFFFFu) > comb) ? 1 : 0;
            int rank = 1 + c2;
            float v = unxform16(comb >> 12);
            if (!m && rank <= k)
                facc += v * (0.5f + ((kf - (float)rank + 1.0f) / kf) * 0.5f);
            else if (m && rank > k)
                facc -= v * (0.5f + (((float)rank - kf) / (float)(B - k)) * 0.5f);
        }
    }

    // below-T matches (rank > k guaranteed): global scans, batch 4 per pass
    uint32_t p0 = 0xFFFFFFFFu, p1 = 0xFFFFFFFFu, p2 = 0xFFFFFFFFu, p3 = 0xFFFFFFFFu;
    int np = 0;
    for (int c = 0; c <= ncand; ++c) {
        bool flushit = (c == ncand);
        if (!flushit) {
            uint32_t cc_ = cand_c[c];
            if ((cc_ & 0x80000000u) && (cc_ & 0x7FFFFFFFu) < combT) {
                uint32_t comb = cc_ & 0x7FFFFFFFu;
                if (np == 0) p0 = comb; else if (np == 1) p1 = comb;
                else if (np == 2) p2 = comb; else p3 = comb;
                ++np;
                flushit = (np == 4);
            }
        }
        if (flushit && np > 0) {
            int c0 = 0, c1 = 0, c2 = 0, c3 = 0;
#pragma unroll
            for (int q = 0; q < 8; ++q) {
                uint32_t u[8] = {kv[q].x & 0xFFFFu, kv[q].x >> 16,
                                 kv[q].y & 0xFFFFu, kv[q].y >> 16,
                                 kv[q].z & 0xFFFFu, kv[q].z >> 16,
                                 kv[q].w & 0xFFFFu, kv[q].w >> 16};
                int jb = (q * 64 + lane) * 8;
#pragma unroll
                for (int cc = 0; cc < 8; ++cc) {
                    uint32_t comb_e = (u[cc] << 12) | (uint32_t)(4095 - (jb + cc));
                    c0 += (comb_e > p0) ? 1 : 0;
                    c1 += (comb_e > p1) ? 1 : 0;
                    c2 += (comb_e > p2) ? 1 : 0;
                    c3 += (comb_e > p3) ? 1 : 0;
                }
            }
#pragma unroll
            for (int off = 32; off > 0; off >>= 1) {
                c0 += __shfl_xor(c0, off); c1 += __shfl_xor(c1, off);
                c2 += __shfl_xor(c2, off); c3 += __shfl_xor(c3, off);
            }
            if (lane == 0) {
                int rk[4] = {1 + c0, 1 + c1, 1 + c2, 1 + c3};
                uint32_t pp[4] = {p0, p1, p2, p3};
                for (int i = 0; i < np; ++i) {
                    float v = unxform16(pp[i] >> 12);
                    facc -= v * (0.5f + (((float)rk[i] - kf) / (float)(B - k)) * 0.5f);
                }
            }
            p0 = p1 = p2 = p3 = 0xFFFFFFFFu;
            np = 0;
        }
    }

#pragma unroll
    for (int off = 32; off > 0; off >>= 1) facc += __shfl_xor(facc, off);
    if (lane == 0) atomicAdd(out, facc);
}

extern "C" void kernel_launch(void* const* d_in, const int* in_sizes, int n_in,
                              void* d_out, int out_size, void* d_ws, size_t ws_size,
                              hipStream_t stream) {
    const float* R      = (const float*)d_in[0];
    const int*   labels = (const int*)d_in[1];
    float* out = (float*)d_out;

    float*          sq   = (float*)d_ws;                                     // 16 KB
    unsigned short* Rb   = (unsigned short*)((char*)d_ws + 16 * 1024);       // 1 MB
    unsigned short* simk = (unsigned short*)((char*)d_ws + 16 * 1024 + 1024 * 1024 + 256);

    hipLaunchKernelGGL(prep_kernel, dim3(B / 4), dim3(256), 0, stream, R, sq, Rb, out);
    hipLaunchKernelGGL(gemm_sim_mfma, dim3(B / 128, B / 128), dim3(256), 0, stream,
                       Rb, sq, labels, simk);
    hipLaunchKernelGGL(row_loss_w64, dim3(B), dim3(64), 0, stream, simk, labels, out);
}

// Round 10
// 134.670 us; speedup vs baseline: 1.4265x; 1.4265x over previous
//
#include <hip/hip_runtime.h>
#include <cstdint>
#include <cstddef>

#define B 4096
#define D 128
#define MARGIN_F 0.2f
#define CW 256            // per-row candidate capacity
#define ROWS 16           // rows per block
#define SSTR 4104         // key-strip stride (ushorts): rows 16B-aligned, bank-skewed

typedef short bf16x8 __attribute__((ext_vector_type(8)));
typedef float f32x4 __attribute__((ext_vector_type(4)));
typedef uint32_t u32x4 __attribute__((ext_vector_type(4)));

// order-preserving float->uint (ascending uint == ascending float)
__device__ __forceinline__ uint32_t xform_key(float f) {
    uint32_t u = __float_as_uint(f);
    return u ^ (uint32_t)((((int32_t)u) >> 31) | 0x80000000);
}
// decode 16-bit truncated key (bucket center under round-to-nearest encode)
__device__ __forceinline__ float unxform16(uint32_t k16) {
    uint32_t u = k16 << 16;
    u = (u & 0x80000000u) ? (u ^ 0x80000000u) : ~u;
    return __uint_as_float(u);
}
__device__ __forceinline__ unsigned short f2bf(float f) {   // round-nearest-even
    uint32_t u = __float_as_uint(f);
    return (unsigned short)((u + 0x7FFFu + ((u >> 16) & 1u)) >> 16);
}

// fused: zero out, sq[i] = ||R[i]||^2, R -> Rb (bf16 rne)
__global__ __launch_bounds__(256) void prep_kernel(const float* __restrict__ R,
                                                   float* __restrict__ sq,
                                                   unsigned short* __restrict__ Rb,
                                                   float* __restrict__ out) {
    if (blockIdx.x == 0 && threadIdx.x == 0) out[0] = 0.0f;
    int wave = threadIdx.x >> 6;
    int lane = threadIdx.x & 63;
    int row  = blockIdx.x * 4 + wave;
    const float2* R2 = (const float2*)R + (size_t)row * (D / 2);
    float2 v = R2[lane];
    ushort2 o; o.x = f2bf(v.x); o.y = f2bf(v.y);
    *(ushort2*)(Rb + (size_t)row * D + lane * 2) = o;
    float s = v.x * v.x + v.y * v.y;
#pragma unroll
    for (int off = 32; off > 0; off >>= 1) s += __shfl_down(s, off);
    if (lane == 0) sq[row] = s;
}

// FUSED: 16 rows/block. Phase 1: MFMA gram (A = own rows in registers,
// B = Rb streamed from L2) + dist/margin -> 16-bit keys in a 128KB LDS strip.
// Phase 2: r8's per-wave threshold/rank machinery reading keys from LDS.
// simk (the 32MB global handoff) no longer exists.
__global__ __launch_bounds__(512) void fused_loss(const unsigned short* __restrict__ Rb,
                                                  const float* __restrict__ sq,
                                                  const int* __restrict__ labels,
                                                  float* __restrict__ out) {
    __shared__ unsigned short S[ROWS * SSTR];      // 131,328 B key strip
    __shared__ uint32_t cand_c[ROWS][CW];          // 16 KB: comb | (match<<31)
    __shared__ int cnt[ROWS];

    const int tid  = threadIdx.x;
    const int wid  = tid >> 6, lane = tid & 63;
    const int q    = lane >> 4, t = lane & 15;
    const int r0   = blockIdx.x * ROWS;

    if (tid < ROWS) cnt[tid] = 0;

    // ---- phase 1: A fragments for the block's 16 rows (held in registers)
    bf16x8 af[4];
    const unsigned short* baseA = Rb + (size_t)(r0 + t) * D + q * 8;
#pragma unroll
    for (int kq = 0; kq < 4; ++kq)
        af[kq] = *(const bf16x8*)(baseA + kq * 32);

    float sqa[4]; int la[4];                       // epilogue row scalars (row = q*4+rr)
#pragma unroll
    for (int rr = 0; rr < 4; ++rr) {
        sqa[rr] = sq[r0 + q * 4 + rr];
        la[rr]  = labels[r0 + q * 4 + rr];
    }

    // 256 j-tiles of 16 cols; 8 waves -> 32 tiles/wave
    for (int i = 0; i < 32; ++i) {
        const int jt  = wid * 32 + i;
        const int col = jt * 16 + t;
        const unsigned short* baseB = Rb + (size_t)col * D + q * 8;
        bf16x8 bfr[4];
#pragma unroll
        for (int kq = 0; kq < 4; ++kq)
            bfr[kq] = *(const bf16x8*)(baseB + kq * 32);
        f32x4 acc = (f32x4)0.0f;
#pragma unroll
        for (int kq = 0; kq < 4; ++kq)
            acc = __builtin_amdgcn_mfma_f32_16x16x32_bf16(af[kq], bfr[kq], acc, 0, 0, 0);

        const float sqc = sq[col];
        const int   lc  = labels[col];
#pragma unroll
        for (int rr = 0; rr < 4; ++rr) {           // D: row = q*4+rr, col = t
            float g  = acc[rr];
            float d2 = fmaxf(sqa[rr] + sqc - 2.0f * g, 0.0f);
            float dist = (d2 > 0.0f) ? sqrtf(d2) : 0.0f;
            float s = -dist + ((la[rr] == lc) ? 0.0f : MARGIN_F);
            uint32_t key = xform_key(s);           // sim <= 0.2 -> no ovf on +0x8000
            S[(q * 4 + rr) * SSTR + col] = (unsigned short)((key + 0x8000u) >> 16);
        }
    }
    __syncthreads();                               // strip complete; cnt[] visible

    // ---- phase 2: each wave owns 2 rows; keys kv[8] from LDS (b128, aligned)
    float facc = 0.0f;
    const int4* lv = (const int4*)labels;

    for (int rr2 = 0; rr2 < 2; ++rr2) {
        const int row  = wid * 2 + rr2;
        const int grow = r0 + row;
        const int li   = labels[grow];

        u32x4 kv[8];
#pragma unroll
        for (int qq = 0; qq < 8; ++qq)
            kv[qq] = *(u32x4*)(&S[row * SSTR + (qq * 64 + lane) * 8]);

        uint64_t mbits = 0;
        uint32_t t1 = 0, t2 = 0;
#pragma unroll
        for (int qq = 0; qq < 8; ++qq) {
            const int lb = (qq * 64 + lane) * 2;
            int4 la4 = lv[lb], lc4 = lv[lb + 1];
            uint32_t u[8] = {kv[qq].x & 0xFFFFu, kv[qq].x >> 16,
                             kv[qq].y & 0xFFFFu, kv[qq].y >> 16,
                             kv[qq].z & 0xFFFFu, kv[qq].z >> 16,
                             kv[qq].w & 0xFFFFu, kv[qq].w >> 16};
#pragma unroll
            for (int c = 0; c < 8; ++c) {
                uint32_t mn = min(t1, u[c]);
                t1 = max(t1, u[c]);
                t2 = max(t2, mn);
            }
            mbits |= (uint64_t)(la4.x == li) << (qq * 8 + 0);
            mbits |= (uint64_t)(la4.y == li) << (qq * 8 + 1);
            mbits |= (uint64_t)(la4.z == li) << (qq * 8 + 2);
            mbits |= (uint64_t)(la4.w == li) << (qq * 8 + 3);
            mbits |= (uint64_t)(lc4.x == li) << (qq * 8 + 4);
            mbits |= (uint64_t)(lc4.y == li) << (qq * 8 + 5);
            mbits |= (uint64_t)(lc4.z == li) << (qq * 8 + 6);
            mbits |= (uint64_t)(lc4.w == li) << (qq * 8 + 7);
        }

        int kloc = __popcll(mbits);
#pragma unroll
        for (int off = 32; off > 0; off >>= 1) kloc += __shfl_xor(kloc, off);
        const int k = kloc;
        const float kf = (float)k;

        // ballot binary search: T = k-th largest of 128-subset (<= true k-th)
        const int kneed = min(k, 128);
        uint32_t T = 0;
#pragma unroll
        for (int b = 15; b >= 0; --b) {
            uint32_t g = T | (1u << b);
            int c = __popcll(__ballot(t1 >= g)) + __popcll(__ballot(t2 >= g));
            if (c >= kneed) T = g;
        }
        const uint32_t combT = T << 12;

        // gather candidates = {u >= T} U {matches}; comb = (u<<12)|(4095-j)
#pragma unroll
        for (int qq = 0; qq < 8; ++qq) {
            uint32_t u[8] = {kv[qq].x & 0xFFFFu, kv[qq].x >> 16,
                             kv[qq].y & 0xFFFFu, kv[qq].y >> 16,
                             kv[qq].z & 0xFFFFu, kv[qq].z >> 16,
                             kv[qq].w & 0xFFFFu, kv[qq].w >> 16};
            int jb = (qq * 64 + lane) * 8;
#pragma unroll
            for (int c = 0; c < 8; ++c) {
                int e = qq * 8 + c;
                uint32_t m = (uint32_t)((mbits >> e) & 1);
                if (u[c] >= T || m) {
                    int p = atomicAdd(&cnt[row], 1);
                    if (p < CW)
                        cand_c[row][p] = (u[c] << 12) | (uint32_t)(4095 - (jb + c)) | (m << 31);
                }
            }
        }
        const int ncand = min(cnt[row], CW);

        // candidate-internal exact ranks for u >= T (every beater is a candidate)
        for (int s = lane; s < ncand; s += 64) {
            uint32_t cs = cand_c[row][s];
            uint32_t comb = cs & 0x7FFFFFFFu;
            int m = (int)(cs >> 31);
            if (comb >= combT) {
                int c2 = 0;
                for (int c = 0; c < ncand; ++c)
                    c2 += ((cand_c[row][c] & 0x7FFFFFFFu) > comb) ? 1 : 0;
                int rank = 1 + c2;
                float v = unxform16(comb >> 12);
                if (!m && rank <= k)
                    facc += v * (0.5f + ((kf - (float)rank + 1.0f) / kf) * 0.5f);
                else if (m && rank > k)
                    facc -= v * (0.5f + (((float)rank - kf) / (float)(B - k)) * 0.5f);
            }
        }

        // below-T matches (rank > k guaranteed): register scans, batch 4
        uint32_t p0 = 0xFFFFFFFFu, p1 = 0xFFFFFFFFu, p2 = 0xFFFFFFFFu, p3 = 0xFFFFFFFFu;
        int np = 0;
        for (int c = 0; c <= ncand; ++c) {
            bool flushit = (c == ncand);
            if (!flushit) {
                uint32_t cc_ = cand_c[row][c];
                if ((cc_ & 0x80000000u) && (cc_ & 0x7FFFFFFFu) < combT) {
                    uint32_t comb = cc_ & 0x7FFFFFFFu;
                    if (np == 0) p0 = comb; else if (np == 1) p1 = comb;
                    else if (np == 2) p2 = comb; else p3 = comb;
                    ++np;
                    flushit = (np == 4);
                }
            }
            if (flushit && np > 0) {
                int c0 = 0, c1 = 0, c2 = 0, c3 = 0;
#pragma unroll
                for (int qq = 0; qq < 8; ++qq) {
                    uint32_t u[8] = {kv[qq].x & 0xFFFFu, kv[qq].x >> 16,
                                     kv[qq].y & 0xFFFFu, kv[qq].y >> 16,
                                     kv[qq].z & 0xFFFFu, kv[qq].z >> 16,
                                     kv[qq].w & 0xFFFFu, kv[qq].w >> 16};
                    int jb = (qq * 64 + lane) * 8;
#pragma unroll
                    for (int cc = 0; cc < 8; ++cc) {
                        uint32_t comb_e = (u[cc] << 12) | (uint32_t)(4095 - (jb + cc));
                        c0 += (comb_e > p0) ? 1 : 0;
                        c1 += (comb_e > p1) ? 1 : 0;
                        c2 += (comb_e > p2) ? 1 : 0;
                        c3 += (comb_e > p3) ? 1 : 0;
                    }
                }
#pragma unroll
                for (int off = 32; off > 0; off >>= 1) {
                    c0 += __shfl_xor(c0, off); c1 += __shfl_xor(c1, off);
                    c2 += __shfl_xor(c2, off); c3 += __shfl_xor(c3, off);
                }
                if (lane == 0) {
                    int rk[4] = {1 + c0, 1 + c1, 1 + c2, 1 + c3};
                    uint32_t pp[4] = {p0, p1, p2, p3};
                    for (int ii = 0; ii < np; ++ii) {
                        float v = unxform16(pp[ii] >> 12);
                        facc -= v * (0.5f + (((float)rk[ii] - kf) / (float)(B - k)) * 0.5f);
                    }
                }
                p0 = p1 = p2 = p3 = 0xFFFFFFFFu;
                np = 0;
            }
        }
    }

#pragma unroll
    for (int off = 32; off > 0; off >>= 1) facc += __shfl_xor(facc, off);
    if (lane == 0) atomicAdd(out, facc);
}

extern "C" void kernel_launch(void* const* d_in, const int* in_sizes, int n_in,
                              void* d_out, int out_size, void* d_ws, size_t ws_size,
                              hipStream_t stream) {
    const float* R      = (const float*)d_in[0];
    const int*   labels = (const int*)d_in[1];
    float* out = (float*)d_out;

    float*          sq = (float*)d_ws;                               // 16 KB
    unsigned short* Rb = (unsigned short*)((char*)d_ws + 16 * 1024); // 1 MB

    hipLaunchKernelGGL(prep_kernel, dim3(B / 4), dim3(256), 0, stream, R, sq, Rb, out);
    hipLaunchKernelGGL(fused_loss, dim3(B / ROWS), dim3(512), 0, stream,
                       Rb, sq, labels, out);
}